// Round 2
// baseline (261.130 us; speedup 1.0000x reference)
//
#include <hip/hip_runtime.h>
#include <math.h>

#define BB 4
#define LL 2048
#define KK 30
#define HIDD 128
#define EDGEE 16
#define NLL 3
#define NHH 4
#define HDD 32
#define SCALE_ 0.17677669529663687f  /* 32^-0.5 */

// ---------------------------------------------------------------------------
// QKV projection: out = h @ W + b for W in {Wq,Wk,Wv}.
// Grid: (rows/64, 6): blockIdx.y>>1 selects projection, &1 selects col-half.
// Block 256 threads, tile 64 rows x 64 cols, per-thread 4x4, fp32.
// ---------------------------------------------------------------------------
__global__ __launch_bounds__(256) void qkv_kernel(
    const float* __restrict__ h,
    const float* __restrict__ Wq, const float* __restrict__ bq,
    const float* __restrict__ Wk, const float* __restrict__ bk,
    const float* __restrict__ Wv, const float* __restrict__ bv,
    float* __restrict__ Qp, float* __restrict__ Kp, float* __restrict__ Vp)
{
    __shared__ float Ws[HIDD * 64];   // [k][c] col-half
    __shared__ float xs[HIDD * 68];   // [k][r], pad 68

    const int t = threadIdx.x;
    const int proj = blockIdx.y >> 1;
    const int ch = blockIdx.y & 1;
    const float* W; const float* bias; float* out;
    if (proj == 0)      { W = Wq; bias = bq; out = Qp; }
    else if (proj == 1) { W = Wk; bias = bk; out = Kp; }
    else                { W = Wv; bias = bv; out = Vp; }

    // load W col-half into LDS (float4 coalesced)
    {
        const float4* W4 = (const float4*)W;   // [128][32]
        float4* Ws4 = (float4*)Ws;             // [128][16]
        for (int i = t; i < HIDD * 16; i += 256) {
            int k = i >> 4, cf = i & 15;
            Ws4[i] = W4[k * 32 + ch * 16 + cf];
        }
    }
    // load x tile (64 rows) transposed into xs[k][r]
    const int row0 = blockIdx.x * 64;
    {
        int k = t & 127, r0 = t >> 7;
        #pragma unroll
        for (int i2 = 0; i2 < 32; ++i2) {
            int rr = r0 + i2 * 2;
            xs[k * 68 + rr] = h[(size_t)(row0 + rr) * HIDD + k];
        }
    }
    __syncthreads();

    const int cq = (t & 15) * 4;   // col base within half
    const int rq = (t >> 4) * 4;   // row base within tile
    float acc[4][4] = {};
    #pragma unroll 8
    for (int k = 0; k < HIDD; ++k) {
        float4 a = *(const float4*)&xs[k * 68 + rq];
        float4 w = *(const float4*)&Ws[k * 64 + cq];
        float av[4] = {a.x, a.y, a.z, a.w};
        float wv[4] = {w.x, w.y, w.z, w.w};
        #pragma unroll
        for (int i = 0; i < 4; ++i)
            #pragma unroll
            for (int j = 0; j < 4; ++j)
                acc[i][j] = fmaf(av[i], wv[j], acc[i][j]);
    }
    float4 b4 = *(const float4*)&bias[ch * 64 + cq];
    float bvv[4] = {b4.x, b4.y, b4.z, b4.w};
    #pragma unroll
    for (int i = 0; i < 4; ++i) {
        int row = row0 + rq + i;
        float4 o4 = make_float4(acc[i][0] + bvv[0], acc[i][1] + bvv[1],
                                acc[i][2] + bvv[2], acc[i][3] + bvv[3]);
        *(float4*)&out[(size_t)row * HIDD + ch * 64 + cq] = o4;
    }
}

// ---------------------------------------------------------------------------
// Attention: one block (128 threads) per (b,l). Gathers projected K/V rows.
// widx holds GLOBAL row ids (b*L + local edge idx).
// ---------------------------------------------------------------------------
__global__ __launch_bounds__(128) void attn_kernel(
    const float* __restrict__ Qp, const float* __restrict__ Kp,
    const float* __restrict__ Vp,
    const int* __restrict__ edge_idxs, const float* __restrict__ h_edges,
    const float* __restrict__ We, const float* __restrict__ be,
    const float* __restrict__ mask, float* __restrict__ o_out)
{
    __shared__ float We_s[EDGEE * NHH];
    __shared__ int   widx[KK];
    __shared__ float nms[KK];
    __shared__ float sc_s[KK * NHH];

    const int row = blockIdx.x;          // b*L + l
    const int b = row >> 11;             // / 2048
    const int t = threadIdx.x;           // d in [0,128)
    const int hh = t >> 5;               // head

    if (t < EDGEE * NHH) We_s[t] = We[t];
    if (t < KK) {
        int gid = b * LL + edge_idxs[(size_t)row * KK + t];  // GLOBAL row
        widx[t] = gid;
        nms[t] = mask[gid];
    }
    __syncthreads();

    // edge bias -> sc_s[k*4+h]
    if (t < KK * NHH) {
        int k = t >> 2, eh = t & 3;
        const float* er = &h_edges[((size_t)row * KK + k) * EDGEE];
        float eb = be[eh];
        #pragma unroll
        for (int e = 0; e < EDGEE; ++e) eb = fmaf(er[e], We_s[e * NHH + eh], eb);
        sc_s[t] = eb;
    }
    const float q = Qp[(size_t)row * HIDD + t];
    const float mc = mask[row];
    __syncthreads();

    // scores: q . k per head, + bias, mask
    for (int k = 0; k < KK; ++k) {
        int id = widx[k];
        float kv = Kp[(size_t)id * HIDD + t];
        float p = q * kv;
        p += __shfl_xor(p, 16, 32);
        p += __shfl_xor(p, 8, 32);
        p += __shfl_xor(p, 4, 32);
        p += __shfl_xor(p, 2, 32);
        p += __shfl_xor(p, 1, 32);
        if ((t & 31) == 0) {
            float am = mc * nms[k];
            sc_s[k * NHH + hh] = (am == 0.f) ? -1e9f
                                             : fmaf(p, SCALE_, sc_s[k * NHH + hh]);
        }
    }
    __syncthreads();

    // softmax over K + weighted V sum
    float m = -1e30f;
    #pragma unroll
    for (int k = 0; k < KK; ++k) m = fmaxf(m, sc_s[k * NHH + hh]);
    float sum = 0.f, o = 0.f;
    for (int k = 0; k < KK; ++k) {
        float w = __expf(sc_s[k * NHH + hh] - m);
        sum += w;
        o = fmaf(w, Vp[(size_t)widx[k] * HIDD + t], o);
    }
    o_out[(size_t)row * HIDD + t] = o / sum;
}

// ---------------------------------------------------------------------------
// Output projection + residual + layernorm + mask.
// ---------------------------------------------------------------------------
__global__ __launch_bounds__(256) void outproj_kernel(
    const float* __restrict__ o_in, const float* __restrict__ Wo,
    const float* __restrict__ bo, const float* __restrict__ h,
    const float* __restrict__ g, const float* __restrict__ bb,
    const float* __restrict__ mask, float* __restrict__ out)
{
    __shared__ float  Ws[HIDD * HIDD];  // 64KB
    __shared__ float  xs[HIDD * 20];    // [k][r], pad 20
    __shared__ float2 red[16 * 32];     // per-row partial (sum, sumsq)

    const int t = threadIdx.x;
    {
        const float4* W4 = (const float4*)Wo;
        float4* Ws4 = (float4*)Ws;
        for (int i = t; i < HIDD * 32; i += 256) Ws4[i] = W4[i];
    }
    const int row0 = blockIdx.x * 16;
    {
        int k = t & 127, r0 = t >> 7;
        #pragma unroll
        for (int i2 = 0; i2 < 8; ++i2) {
            int rr = r0 + i2 * 2;
            xs[k * 20 + rr] = o_in[(size_t)(row0 + rr) * HIDD + k];
        }
    }
    __syncthreads();

    const int cq = (t & 31) * 4;
    const int rg = t >> 5;            // 0..7 -> rows rg*2, rg*2+1
    float acc[2][4] = {};
    #pragma unroll 8
    for (int k = 0; k < HIDD; ++k) {
        float2 a = *(const float2*)&xs[k * 20 + rg * 2];
        float4 w = *(const float4*)&Ws[k * HIDD + cq];
        float av[2] = {a.x, a.y};
        float wv[4] = {w.x, w.y, w.z, w.w};
        #pragma unroll
        for (int i = 0; i < 2; ++i)
            #pragma unroll
            for (int j = 0; j < 4; ++j)
                acc[i][j] = fmaf(av[i], wv[j], acc[i][j]);
    }
    float4 bo4 = *(const float4*)&bo[cq];
    float bv[4] = {bo4.x, bo4.y, bo4.z, bo4.w};
    float y[2][4];
    #pragma unroll
    for (int i = 0; i < 2; ++i) {
        int row = row0 + rg * 2 + i;
        float4 hr = *(const float4*)&h[(size_t)row * HIDD + cq];
        float hv[4] = {hr.x, hr.y, hr.z, hr.w};
        float s1 = 0.f, s2 = 0.f;
        #pragma unroll
        for (int j = 0; j < 4; ++j) {
            y[i][j] = acc[i][j] + bv[j] + hv[j];
            s1 += y[i][j];
            s2 += y[i][j] * y[i][j];
        }
        red[(rg * 2 + i) * 32 + (t & 31)] = make_float2(s1, s2);
    }
    __syncthreads();

    float4 g4 = *(const float4*)&g[cq];
    float4 b4 = *(const float4*)&bb[cq];
    float gv[4] = {g4.x, g4.y, g4.z, g4.w};
    float bbv[4] = {b4.x, b4.y, b4.z, b4.w};
    #pragma unroll
    for (int i = 0; i < 2; ++i) {
        int rl = rg * 2 + i, row = row0 + rl;
        float s1 = 0.f, s2 = 0.f;
        for (int qi = 0; qi < 32; ++qi) {
            float2 rr = red[rl * 32 + qi];
            s1 += rr.x; s2 += rr.y;
        }
        float mu = s1 * (1.f / 128.f);
        float var = s2 * (1.f / 128.f) - mu * mu;
        float rs = rsqrtf(var + 1e-5f);
        float mk = mask[row];
        float4 o4;
        o4.x = ((y[i][0] - mu) * rs * gv[0] + bbv[0]) * mk;
        o4.y = ((y[i][1] - mu) * rs * gv[1] + bbv[1]) * mk;
        o4.z = ((y[i][2] - mu) * rs * gv[2] + bbv[2]) * mk;
        o4.w = ((y[i][3] - mu) * rs * gv[3] + bbv[3]) * mk;
        *(float4*)&out[(size_t)row * HIDD + cq] = o4;
    }
}

extern "C" void kernel_launch(void* const* d_in, const int* in_sizes, int n_in,
                              void* d_out, int out_size, void* d_ws, size_t ws_size,
                              hipStream_t stream) {
    const float* h_nodes = (const float*)d_in[0];
    const float* h_edges = (const float*)d_in[1];
    const float* mask    = (const float*)d_in[2];
    const float* Wq = (const float*)d_in[3];
    const float* bq = (const float*)d_in[4];
    const float* Wk = (const float*)d_in[5];
    const float* bk = (const float*)d_in[6];
    const float* Wv = (const float*)d_in[7];
    const float* bv = (const float*)d_in[8];
    const float* We = (const float*)d_in[9];
    const float* be = (const float*)d_in[10];
    const float* Wo = (const float*)d_in[11];
    const float* bo = (const float*)d_in[12];
    const float* ln_g = (const float*)d_in[13];
    const float* ln_b = (const float*)d_in[14];
    const int* edge_idxs = (const int*)d_in[15];

    float* ws = (float*)d_ws;
    const size_t NTOK = (size_t)BB * LL;           // 8192
    float* h  = ws;
    float* Qp = ws + NTOK * HIDD;
    float* Kp = ws + 2 * NTOK * HIDD;
    float* Vp = ws + 3 * NTOK * HIDD;
    float* ob = ws + 4 * NTOK * HIDD;

    hipMemcpyAsync(h, h_nodes, NTOK * HIDD * sizeof(float),
                   hipMemcpyDeviceToDevice, stream);

    for (int i = 0; i < NLL; ++i) {
        qkv_kernel<<<dim3(NTOK / 64, 6), 256, 0, stream>>>(
            h,
            Wq + (size_t)i * HIDD * HIDD, bq + i * HIDD,
            Wk + (size_t)i * HIDD * HIDD, bk + i * HIDD,
            Wv + (size_t)i * HIDD * HIDD, bv + i * HIDD,
            Qp, Kp, Vp);
        attn_kernel<<<NTOK, 128, 0, stream>>>(
            Qp, Kp, Vp, edge_idxs, h_edges,
            We + i * EDGEE * NHH, be + i * NHH, mask, ob);
        outproj_kernel<<<NTOK / 16, 256, 0, stream>>>(
            ob, Wo + (size_t)i * HIDD * HIDD, bo + i * HIDD,
            h, ln_g + i * HIDD, ln_b + i * HIDD, mask,
            (i == NLL - 1) ? (float*)d_out : h);
    }
}

// Round 3
// 172.417 us; speedup vs baseline: 1.5145x; 1.5145x over previous
//
#include <hip/hip_runtime.h>
#include <math.h>

#define BB 4
#define LL 2048
#define KK 30
#define HIDD 128
#define EDGEE 16
#define NLL 3
#define NHH 4
#define HDD 32
#define SCALE_ 0.17677669529663687f  /* 32^-0.5 */

// ---------------------------------------------------------------------------
// QKV projection: out = h @ W + b for W in {Wq,Wk,Wv}.
// Grid: (rows/64, 6): blockIdx.y>>1 selects projection, &1 selects col-half.
// ---------------------------------------------------------------------------
__global__ __launch_bounds__(256) void qkv_kernel(
    const float* __restrict__ h,
    const float* __restrict__ Wq, const float* __restrict__ bq,
    const float* __restrict__ Wk, const float* __restrict__ bk,
    const float* __restrict__ Wv, const float* __restrict__ bv,
    float* __restrict__ Qp, float* __restrict__ Kp, float* __restrict__ Vp)
{
    __shared__ float Ws[HIDD * 64];   // [k][c] col-half
    __shared__ float xs[HIDD * 68];   // [k][r], pad 68

    const int t = threadIdx.x;
    const int proj = blockIdx.y >> 1;
    const int ch = blockIdx.y & 1;
    const float* W; const float* bias; float* out;
    if (proj == 0)      { W = Wq; bias = bq; out = Qp; }
    else if (proj == 1) { W = Wk; bias = bk; out = Kp; }
    else                { W = Wv; bias = bv; out = Vp; }

    {
        const float4* W4 = (const float4*)W;   // [128][32]
        float4* Ws4 = (float4*)Ws;             // [128][16]
        for (int i = t; i < HIDD * 16; i += 256) {
            int k = i >> 4, cf = i & 15;
            Ws4[i] = W4[k * 32 + ch * 16 + cf];
        }
    }
    const int row0 = blockIdx.x * 64;
    {
        int k = t & 127, r0 = t >> 7;
        #pragma unroll
        for (int i2 = 0; i2 < 32; ++i2) {
            int rr = r0 + i2 * 2;
            xs[k * 68 + rr] = h[(size_t)(row0 + rr) * HIDD + k];
        }
    }
    __syncthreads();

    const int cq = (t & 15) * 4;
    const int rq = (t >> 4) * 4;
    float acc[4][4] = {};
    #pragma unroll 8
    for (int k = 0; k < HIDD; ++k) {
        float4 a = *(const float4*)&xs[k * 68 + rq];
        float4 w = *(const float4*)&Ws[k * 64 + cq];
        float av[4] = {a.x, a.y, a.z, a.w};
        float wv[4] = {w.x, w.y, w.z, w.w};
        #pragma unroll
        for (int i = 0; i < 4; ++i)
            #pragma unroll
            for (int j = 0; j < 4; ++j)
                acc[i][j] = fmaf(av[i], wv[j], acc[i][j]);
    }
    float4 b4 = *(const float4*)&bias[ch * 64 + cq];
    float bvv[4] = {b4.x, b4.y, b4.z, b4.w};
    #pragma unroll
    for (int i = 0; i < 4; ++i) {
        int row = row0 + rq + i;
        float4 o4 = make_float4(acc[i][0] + bvv[0], acc[i][1] + bvv[1],
                                acc[i][2] + bvv[2], acc[i][3] + bvv[3]);
        *(float4*)&out[(size_t)row * HIDD + ch * 64 + cq] = o4;
    }
}

// ---------------------------------------------------------------------------
// Attention v2: 32 lanes per row, lane g owns float4 dims [4g,4g+4).
// 256-thread block = 8 rows. Scores live in 30 regs/lane; softmax lane-local.
// ---------------------------------------------------------------------------
__global__ __launch_bounds__(256) void attn_kernel(
    const float* __restrict__ Qp, const float* __restrict__ Kp,
    const float* __restrict__ Vp,
    const int* __restrict__ edge_idxs, const float* __restrict__ h_edges,
    const float* __restrict__ We, const float* __restrict__ be,
    const float* __restrict__ mask, float* __restrict__ o_out)
{
    __shared__ int   widx[8][KK];
    __shared__ float ams[8][KK];
    __shared__ float ebs[8][KK][NHH];

    const int t = threadIdx.x;
    const int grp = t >> 5;                 // row within block
    const int g = t & 31;                   // lane in group = float4 index
    const int row = blockIdx.x * 8 + grp;   // b*L + l
    const int b = row >> 11;
    const int hh = g >> 3;                  // head of this lane's dims

    // stage: indices, masks, edge bias (lanes 0..29 of each group)
    if (g < KK) {
        int gid = b * LL + edge_idxs[(size_t)row * KK + g];
        widx[grp][g] = gid;
        ams[grp][g] = mask[row] * mask[gid];
        const float* ee = &h_edges[((size_t)row * KK + g) * EDGEE];
        float ebh[NHH] = {be[0], be[1], be[2], be[3]};
        #pragma unroll
        for (int e = 0; e < EDGEE; ++e) {
            float ev = ee[e];
            #pragma unroll
            for (int hq = 0; hq < NHH; ++hq)
                ebh[hq] = fmaf(ev, We[e * NHH + hq], ebh[hq]);
        }
        *(float4*)&ebs[grp][g][0] = make_float4(ebh[0], ebh[1], ebh[2], ebh[3]);
    }
    __syncthreads();

    const float4 q4 = ((const float4*)Qp)[(size_t)row * 32 + g];
    float sc[KK];
    #pragma unroll
    for (int k = 0; k < KK; ++k) {
        int gid = widx[grp][k];
        float4 k4 = ((const float4*)Kp)[(size_t)gid * 32 + g];
        float p = q4.x * k4.x + q4.y * k4.y + q4.z * k4.z + q4.w * k4.w;
        p += __shfl_xor(p, 4, 32);
        p += __shfl_xor(p, 2, 32);
        p += __shfl_xor(p, 1, 32);
        float am = ams[grp][k];
        float eb = ebs[grp][k][hh];
        sc[k] = (am == 0.f) ? -1e9f : fmaf(p, SCALE_, eb);
    }

    // lane-local softmax over K=30
    float m = sc[0];
    #pragma unroll
    for (int k = 1; k < KK; ++k) m = fmaxf(m, sc[k]);
    float sum = 0.f;
    #pragma unroll
    for (int k = 0; k < KK; ++k) { sc[k] = __expf(sc[k] - m); sum += sc[k]; }
    const float inv = 1.f / sum;

    // PV
    float4 o = make_float4(0.f, 0.f, 0.f, 0.f);
    #pragma unroll
    for (int k = 0; k < KK; ++k) {
        int gid = widx[grp][k];
        float4 v4 = ((const float4*)Vp)[(size_t)gid * 32 + g];
        o.x = fmaf(sc[k], v4.x, o.x);
        o.y = fmaf(sc[k], v4.y, o.y);
        o.z = fmaf(sc[k], v4.z, o.z);
        o.w = fmaf(sc[k], v4.w, o.w);
    }
    ((float4*)o_out)[(size_t)row * 32 + g] =
        make_float4(o.x * inv, o.y * inv, o.z * inv, o.w * inv);
}

// ---------------------------------------------------------------------------
// Output projection + residual + layernorm + mask.
// ---------------------------------------------------------------------------
__global__ __launch_bounds__(256) void outproj_kernel(
    const float* __restrict__ o_in, const float* __restrict__ Wo,
    const float* __restrict__ bo, const float* __restrict__ h,
    const float* __restrict__ g, const float* __restrict__ bb,
    const float* __restrict__ mask, float* __restrict__ out)
{
    __shared__ float  Ws[HIDD * HIDD];  // 64KB
    __shared__ float  xs[HIDD * 20];    // [k][r], pad 20
    __shared__ float2 red[16 * 32];

    const int t = threadIdx.x;
    {
        const float4* W4 = (const float4*)Wo;
        float4* Ws4 = (float4*)Ws;
        for (int i = t; i < HIDD * 32; i += 256) Ws4[i] = W4[i];
    }
    const int row0 = blockIdx.x * 16;
    {
        int k = t & 127, r0 = t >> 7;
        #pragma unroll
        for (int i2 = 0; i2 < 8; ++i2) {
            int rr = r0 + i2 * 2;
            xs[k * 20 + rr] = o_in[(size_t)(row0 + rr) * HIDD + k];
        }
    }
    __syncthreads();

    const int cq = (t & 31) * 4;
    const int rg = t >> 5;
    float acc[2][4] = {};
    #pragma unroll 8
    for (int k = 0; k < HIDD; ++k) {
        float2 a = *(const float2*)&xs[k * 20 + rg * 2];
        float4 w = *(const float4*)&Ws[k * HIDD + cq];
        float av[2] = {a.x, a.y};
        float wv[4] = {w.x, w.y, w.z, w.w};
        #pragma unroll
        for (int i = 0; i < 2; ++i)
            #pragma unroll
            for (int j = 0; j < 4; ++j)
                acc[i][j] = fmaf(av[i], wv[j], acc[i][j]);
    }
    float4 bo4 = *(const float4*)&bo[cq];
    float bv[4] = {bo4.x, bo4.y, bo4.z, bo4.w};
    float y[2][4];
    #pragma unroll
    for (int i = 0; i < 2; ++i) {
        int row = row0 + rg * 2 + i;
        float4 hr = *(const float4*)&h[(size_t)row * HIDD + cq];
        float hv[4] = {hr.x, hr.y, hr.z, hr.w};
        float s1 = 0.f, s2 = 0.f;
        #pragma unroll
        for (int j = 0; j < 4; ++j) {
            y[i][j] = acc[i][j] + bv[j] + hv[j];
            s1 += y[i][j];
            s2 += y[i][j] * y[i][j];
        }
        red[(rg * 2 + i) * 32 + (t & 31)] = make_float2(s1, s2);
    }
    __syncthreads();

    float4 g4 = *(const float4*)&g[cq];
    float4 b4 = *(const float4*)&bb[cq];
    float gv[4] = {g4.x, g4.y, g4.z, g4.w};
    float bbv[4] = {b4.x, b4.y, b4.z, b4.w};
    #pragma unroll
    for (int i = 0; i < 2; ++i) {
        int rl = rg * 2 + i, row = row0 + rl;
        float s1 = 0.f, s2 = 0.f;
        for (int qi = 0; qi < 32; ++qi) {
            float2 rr = red[rl * 32 + qi];
            s1 += rr.x; s2 += rr.y;
        }
        float mu = s1 * (1.f / 128.f);
        float var = s2 * (1.f / 128.f) - mu * mu;
        float rs = rsqrtf(var + 1e-5f);
        float mk = mask[row];
        float4 o4;
        o4.x = ((y[i][0] - mu) * rs * gv[0] + bbv[0]) * mk;
        o4.y = ((y[i][1] - mu) * rs * gv[1] + bbv[1]) * mk;
        o4.z = ((y[i][2] - mu) * rs * gv[2] + bbv[2]) * mk;
        o4.w = ((y[i][3] - mu) * rs * gv[3] + bbv[3]) * mk;
        *(float4*)&out[(size_t)row * HIDD + cq] = o4;
    }
}

extern "C" void kernel_launch(void* const* d_in, const int* in_sizes, int n_in,
                              void* d_out, int out_size, void* d_ws, size_t ws_size,
                              hipStream_t stream) {
    const float* h_nodes = (const float*)d_in[0];
    const float* h_edges = (const float*)d_in[1];
    const float* mask    = (const float*)d_in[2];
    const float* Wq = (const float*)d_in[3];
    const float* bq = (const float*)d_in[4];
    const float* Wk = (const float*)d_in[5];
    const float* bk = (const float*)d_in[6];
    const float* Wv = (const float*)d_in[7];
    const float* bv = (const float*)d_in[8];
    const float* We = (const float*)d_in[9];
    const float* be = (const float*)d_in[10];
    const float* Wo = (const float*)d_in[11];
    const float* bo = (const float*)d_in[12];
    const float* ln_g = (const float*)d_in[13];
    const float* ln_b = (const float*)d_in[14];
    const int* edge_idxs = (const int*)d_in[15];

    float* ws = (float*)d_ws;
    const size_t NTOK = (size_t)BB * LL;           // 8192
    float* h  = ws;
    float* Qp = ws + NTOK * HIDD;
    float* Kp = ws + 2 * NTOK * HIDD;
    float* Vp = ws + 3 * NTOK * HIDD;
    float* ob = ws + 4 * NTOK * HIDD;

    for (int i = 0; i < NLL; ++i) {
        const float* h_src = (i == 0) ? h_nodes : h;
        qkv_kernel<<<dim3(NTOK / 64, 6), 256, 0, stream>>>(
            h_src,
            Wq + (size_t)i * HIDD * HIDD, bq + i * HIDD,
            Wk + (size_t)i * HIDD * HIDD, bk + i * HIDD,
            Wv + (size_t)i * HIDD * HIDD, bv + i * HIDD,
            Qp, Kp, Vp);
        attn_kernel<<<NTOK / 8, 256, 0, stream>>>(
            Qp, Kp, Vp, edge_idxs, h_edges,
            We + i * EDGEE * NHH, be + i * NHH, mask, ob);
        outproj_kernel<<<NTOK / 16, 256, 0, stream>>>(
            ob, Wo + (size_t)i * HIDD * HIDD, bo + i * HIDD,
            h_src, ln_g + i * HIDD, ln_b + i * HIDD, mask,
            (i == NLL - 1) ? (float*)d_out : h);
    }
}

// Round 4
// 119.527 us; speedup vs baseline: 2.1847x; 1.4425x over previous
//
#include <hip/hip_runtime.h>
#include <math.h>

#define BB 4
#define LL 2048
#define KK 30
#define HIDD 128
#define EDGEE 16
#define NLL 3
#define NHH 4
#define SCALE_ 0.17677669529663687f  /* 32^-0.5 */

typedef __attribute__((ext_vector_type(8))) short bf16x8;
typedef __attribute__((ext_vector_type(4))) float f32x4;

__device__ __forceinline__ ushort f2b(float f) {
    union { float f; uint u; } x; x.f = f;
    uint r = x.u + 0x7fff + ((x.u >> 16) & 1);   // RNE
    return (ushort)(r >> 16);
}

// ---------------------------------------------------------------------------
// One-time cast: h_nodes -> bf16, and all 12 weight mats -> transposed bf16
// WbT[m][n][k] = W_m[k][n], m = layer*4 + {q,k,v,o}
// ---------------------------------------------------------------------------
__global__ __launch_bounds__(256) void cast_kernel(
    const float* __restrict__ h_nodes,
    const float* __restrict__ Wq, const float* __restrict__ Wk,
    const float* __restrict__ Wv, const float* __restrict__ Wo,
    ushort* __restrict__ hb, ushort* __restrict__ WbT)
{
    const int id = blockIdx.x * 256 + threadIdx.x;
    if (blockIdx.y == 0) {
        if (id < 12 * 128 * 128) {
            int m = id >> 14;
            int rem = id & 16383;
            int k = rem >> 7, n = rem & 127;     // n fast -> coalesced read
            int layer = m >> 2, p = m & 3;
            const float* src;
            if (p == 0)      src = Wq + (size_t)layer * 16384;
            else if (p == 1) src = Wk + (size_t)layer * 16384;
            else if (p == 2) src = Wv + (size_t)layer * 16384;
            else             src = Wo + (size_t)layer * 16384;
            WbT[(size_t)m * 16384 + n * 128 + k] = f2b(src[k * 128 + n]);
        }
    } else {
        float4 v = ((const float4*)h_nodes)[id];
        ushort4 o;
        o.x = f2b(v.x); o.y = f2b(v.y); o.z = f2b(v.z); o.w = f2b(v.w);
        ((ushort4*)hb)[id] = o;
    }
}

// ---------------------------------------------------------------------------
// QKV projection via bf16 MFMA: out = hb @ W + b. Grid (64, 3proj), 256 thr.
// Tile 128x128, K=128 single-shot LDS. XOR-swizzled LDS (G4 pattern).
// ---------------------------------------------------------------------------
__global__ __launch_bounds__(256) void qkv_mfma(
    const ushort* __restrict__ hb, const ushort* __restrict__ WbT,
    const float* __restrict__ bq, const float* __restrict__ bk,
    const float* __restrict__ bv,
    float* __restrict__ Qp, float* __restrict__ Kp, float* __restrict__ Vp)
{
    __shared__ ushort As[128 * 128];   // [row][k] swizzled
    __shared__ ushort Bs[128 * 128];   // [col][k] swizzled

    const int t = threadIdx.x;
    const int proj = blockIdx.y;
    const ushort* W = WbT + (size_t)proj * 16384;
    const float* bias = proj == 0 ? bq : (proj == 1 ? bk : bv);
    float* out = proj == 0 ? Qp : (proj == 1 ? Kp : Vp);
    const int row0 = blockIdx.x * 128;

    const uint4* hb4 = (const uint4*)(hb + (size_t)row0 * 128);
    const uint4* W4 = (const uint4*)W;
    #pragma unroll
    for (int i = 0; i < 8; ++i) {
        int c = t + i * 256;                 // 16B-chunk id, 0..2047
        int r = c >> 4, kc = c & 15;
        int off = (r * 256 + kc * 16) ^ ((r & 7) << 4);
        *(uint4*)((char*)As + off) = hb4[c];
        *(uint4*)((char*)Bs + off) = W4[c];
    }
    __syncthreads();

    const int wid = t >> 6, l = t & 63;
    const int lr = l & 15, lg = l >> 4;
    const int rbase = wid * 32;
    f32x4 acc[2][8];
    #pragma unroll
    for (int m = 0; m < 2; ++m)
        #pragma unroll
        for (int n = 0; n < 8; ++n) acc[m][n] = (f32x4){0.f, 0.f, 0.f, 0.f};

    #pragma unroll
    for (int ks = 0; ks < 4; ++ks) {
        const int kb = (lg * 8 + ks * 32) * 2;   // byte offset of lane's k-slice
        bf16x8 a[2], b[8];
        #pragma unroll
        for (int m = 0; m < 2; ++m) {
            int row = rbase + m * 16 + lr;
            a[m] = *(const bf16x8*)((const char*)As + ((row * 256 + kb) ^ ((row & 7) << 4)));
        }
        #pragma unroll
        for (int n = 0; n < 8; ++n) {
            int col = n * 16 + lr;
            b[n] = *(const bf16x8*)((const char*)Bs + ((col * 256 + kb) ^ ((col & 7) << 4)));
        }
        #pragma unroll
        for (int m = 0; m < 2; ++m)
            #pragma unroll
            for (int n = 0; n < 8; ++n)
                acc[m][n] = __builtin_amdgcn_mfma_f32_16x16x32_bf16(a[m], b[n], acc[m][n], 0, 0, 0);
    }

    #pragma unroll
    for (int n = 0; n < 8; ++n) {
        int col = n * 16 + lr;
        float bc = bias[col];
        #pragma unroll
        for (int m = 0; m < 2; ++m)
            #pragma unroll
            for (int r = 0; r < 4; ++r) {
                int row = row0 + rbase + m * 16 + lg * 4 + r;
                out[(size_t)row * 128 + col] = acc[m][n][r] + bc;
            }
    }
}

// ---------------------------------------------------------------------------
// Attention: 32 lanes per row, lane g owns float4 dims [4g,4g+4).
// Writes bf16 output (feeds outproj MFMA A operand).
// ---------------------------------------------------------------------------
__global__ __launch_bounds__(256) void attn_kernel(
    const float* __restrict__ Qp, const float* __restrict__ Kp,
    const float* __restrict__ Vp,
    const int* __restrict__ edge_idxs, const float* __restrict__ h_edges,
    const float* __restrict__ We, const float* __restrict__ be,
    const float* __restrict__ mask, ushort* __restrict__ o_out)
{
    __shared__ int   widx[8][KK];
    __shared__ float ams[8][KK];
    __shared__ float ebs[8][KK][NHH];

    const int t = threadIdx.x;
    const int grp = t >> 5;
    const int g = t & 31;
    const int row = blockIdx.x * 8 + grp;
    const int b = row >> 11;
    const int hh = g >> 3;

    if (g < KK) {
        int gid = b * LL + edge_idxs[(size_t)row * KK + g];
        widx[grp][g] = gid;
        ams[grp][g] = mask[row] * mask[gid];
        const float* ee = &h_edges[((size_t)row * KK + g) * EDGEE];
        float ebh[NHH] = {be[0], be[1], be[2], be[3]};
        #pragma unroll
        for (int e = 0; e < EDGEE; ++e) {
            float ev = ee[e];
            #pragma unroll
            for (int hq = 0; hq < NHH; ++hq)
                ebh[hq] = fmaf(ev, We[e * NHH + hq], ebh[hq]);
        }
        *(float4*)&ebs[grp][g][0] = make_float4(ebh[0], ebh[1], ebh[2], ebh[3]);
    }
    __syncthreads();

    const float4 q4 = ((const float4*)Qp)[(size_t)row * 32 + g];
    float sc[KK];
    #pragma unroll
    for (int k = 0; k < KK; ++k) {
        int gid = widx[grp][k];
        float4 k4 = ((const float4*)Kp)[(size_t)gid * 32 + g];
        float p = q4.x * k4.x + q4.y * k4.y + q4.z * k4.z + q4.w * k4.w;
        p += __shfl_xor(p, 4, 32);
        p += __shfl_xor(p, 2, 32);
        p += __shfl_xor(p, 1, 32);
        float am = ams[grp][k];
        float eb = ebs[grp][k][hh];
        sc[k] = (am == 0.f) ? -1e9f : fmaf(p, SCALE_, eb);
    }

    float m = sc[0];
    #pragma unroll
    for (int k = 1; k < KK; ++k) m = fmaxf(m, sc[k]);
    float sum = 0.f;
    #pragma unroll
    for (int k = 0; k < KK; ++k) { sc[k] = __expf(sc[k] - m); sum += sc[k]; }
    const float inv = 1.f / sum;

    float4 o = make_float4(0.f, 0.f, 0.f, 0.f);
    #pragma unroll
    for (int k = 0; k < KK; ++k) {
        int gid = widx[grp][k];
        float4 v4 = ((const float4*)Vp)[(size_t)gid * 32 + g];
        o.x = fmaf(sc[k], v4.x, o.x);
        o.y = fmaf(sc[k], v4.y, o.y);
        o.z = fmaf(sc[k], v4.z, o.z);
        o.w = fmaf(sc[k], v4.w, o.w);
    }
    ushort4 ob;
    ob.x = f2b(o.x * inv); ob.y = f2b(o.y * inv);
    ob.z = f2b(o.z * inv); ob.w = f2b(o.w * inv);
    ((ushort4*)o_out)[(size_t)row * 32 + g] = ob;
}

// ---------------------------------------------------------------------------
// Output projection via bf16 MFMA + bias + residual + LN + mask.
// Writes fp32 h (or d_out) AND bf16 h for next layer's qkv.
// ---------------------------------------------------------------------------
__global__ __launch_bounds__(256) void outproj_mfma(
    const ushort* __restrict__ obb, const ushort* __restrict__ WoT,
    const float* __restrict__ bo, const float* __restrict__ hres,
    const float* __restrict__ g, const float* __restrict__ bb,
    const float* __restrict__ mask, float* __restrict__ hout,
    ushort* __restrict__ hbout)
{
    __shared__ ushort As[128 * 128];
    __shared__ ushort Bs[128 * 128];

    const int t = threadIdx.x;
    const int row0 = blockIdx.x * 128;

    const uint4* A4 = (const uint4*)(obb + (size_t)row0 * 128);
    const uint4* W4 = (const uint4*)WoT;
    #pragma unroll
    for (int i = 0; i < 8; ++i) {
        int c = t + i * 256;
        int r = c >> 4, kc = c & 15;
        int off = (r * 256 + kc * 16) ^ ((r & 7) << 4);
        *(uint4*)((char*)As + off) = A4[c];
        *(uint4*)((char*)Bs + off) = W4[c];
    }
    __syncthreads();

    const int wid = t >> 6, l = t & 63;
    const int lr = l & 15, lg = l >> 4;
    const int rbase = wid * 32;
    f32x4 acc[2][8];
    #pragma unroll
    for (int m = 0; m < 2; ++m)
        #pragma unroll
        for (int n = 0; n < 8; ++n) acc[m][n] = (f32x4){0.f, 0.f, 0.f, 0.f};

    #pragma unroll
    for (int ks = 0; ks < 4; ++ks) {
        const int kb = (lg * 8 + ks * 32) * 2;
        bf16x8 a[2], b[8];
        #pragma unroll
        for (int m = 0; m < 2; ++m) {
            int row = rbase + m * 16 + lr;
            a[m] = *(const bf16x8*)((const char*)As + ((row * 256 + kb) ^ ((row & 7) << 4)));
        }
        #pragma unroll
        for (int n = 0; n < 8; ++n) {
            int col = n * 16 + lr;
            b[n] = *(const bf16x8*)((const char*)Bs + ((col * 256 + kb) ^ ((col & 7) << 4)));
        }
        #pragma unroll
        for (int m = 0; m < 2; ++m)
            #pragma unroll
            for (int n = 0; n < 8; ++n)
                acc[m][n] = __builtin_amdgcn_mfma_f32_16x16x32_bf16(a[m], b[n], acc[m][n], 0, 0, 0);
    }

    // epilogue: y = acc + bo + residual; LN stats per row; normalize; mask
    float s1[2][4] = {}, s2[2][4] = {};
    #pragma unroll
    for (int n = 0; n < 8; ++n) {
        int col = n * 16 + lr;
        float boc = bo[col];
        #pragma unroll
        for (int m = 0; m < 2; ++m)
            #pragma unroll
            for (int r = 0; r < 4; ++r) {
                int row = row0 + rbase + m * 16 + lg * 4 + r;
                float v = acc[m][n][r] + boc + hres[(size_t)row * 128 + col];
                acc[m][n][r] = v;
                s1[m][r] += v;
                s2[m][r] += v * v;
            }
    }
    #pragma unroll
    for (int m = 0; m < 2; ++m)
        #pragma unroll
        for (int r = 0; r < 4; ++r) {
            float a = s1[m][r], b2 = s2[m][r];
            #pragma unroll
            for (int d = 1; d < 16; d <<= 1) {
                a  += __shfl_xor(a, d, 64);
                b2 += __shfl_xor(b2, d, 64);
            }
            s1[m][r] = a; s2[m][r] = b2;
        }

    float gv[8], bbv[8];
    #pragma unroll
    for (int n = 0; n < 8; ++n) { gv[n] = g[n * 16 + lr]; bbv[n] = bb[n * 16 + lr]; }

    #pragma unroll
    for (int m = 0; m < 2; ++m)
        #pragma unroll
        for (int r = 0; r < 4; ++r) {
            int row = row0 + rbase + m * 16 + lg * 4 + r;
            float mu = s1[m][r] * (1.f / 128.f);
            float var = s2[m][r] * (1.f / 128.f) - mu * mu;
            float rs = rsqrtf(var + 1e-5f);
            float mk = mask[row];
            #pragma unroll
            for (int n = 0; n < 8; ++n) {
                int col = n * 16 + lr;
                float val = ((acc[m][n][r] - mu) * rs * gv[n] + bbv[n]) * mk;
                hout[(size_t)row * 128 + col] = val;
                hbout[(size_t)row * 128 + col] = f2b(val);
            }
        }
}

extern "C" void kernel_launch(void* const* d_in, const int* in_sizes, int n_in,
                              void* d_out, int out_size, void* d_ws, size_t ws_size,
                              hipStream_t stream) {
    const float* h_nodes = (const float*)d_in[0];
    const float* h_edges = (const float*)d_in[1];
    const float* mask    = (const float*)d_in[2];
    const float* Wq = (const float*)d_in[3];
    const float* bq = (const float*)d_in[4];
    const float* Wk = (const float*)d_in[5];
    const float* bk = (const float*)d_in[6];
    const float* Wv = (const float*)d_in[7];
    const float* bv = (const float*)d_in[8];
    const float* We = (const float*)d_in[9];
    const float* be = (const float*)d_in[10];
    const float* Wo = (const float*)d_in[11];
    const float* bo = (const float*)d_in[12];
    const float* ln_g = (const float*)d_in[13];
    const float* ln_b = (const float*)d_in[14];
    const int* edge_idxs = (const int*)d_in[15];

    float* ws = (float*)d_ws;
    const size_t NTOK = (size_t)BB * LL;           // 8192
    const size_t NE = NTOK * HIDD;                 // 1048576
    float* h  = ws;
    float* Qp = ws + NE;
    float* Kp = ws + 2 * NE;
    float* Vp = ws + 3 * NE;
    ushort* obb = (ushort*)(ws + 4 * NE);
    ushort* hb  = obb + NE;
    ushort* WbT = hb + NE;

    cast_kernel<<<dim3(1024, 2), 256, 0, stream>>>(h_nodes, Wq, Wk, Wv, Wo, hb, WbT);

    for (int i = 0; i < NLL; ++i) {
        qkv_mfma<<<dim3(NTOK / 128, 3), 256, 0, stream>>>(
            hb, WbT + (size_t)i * 4 * 16384,
            bq + i * HIDD, bk + i * HIDD, bv + i * HIDD,
            Qp, Kp, Vp);
        attn_kernel<<<NTOK / 8, 256, 0, stream>>>(
            Qp, Kp, Vp, edge_idxs, h_edges,
            We + i * EDGEE * NHH, be + i * NHH, mask, obb);
        outproj_mfma<<<NTOK / 128, 256, 0, stream>>>(
            obb, WbT + ((size_t)i * 4 + 3) * 16384, bo + i * HIDD,
            (i == 0) ? h_nodes : h,
            ln_g + i * HIDD, ln_b + i * HIDD, mask,
            (i == NLL - 1) ? (float*)d_out : h, hb);
    }
}